// Round 4
// baseline (530.122 us; speedup 1.0000x reference)
//
#include <hip/hip_runtime.h>
#include <cstdint>
#include <cstddef>

// R9: persistent GRU with COLUMN ownership (R5 partition: block = 256 samples
// x 32 jc x 3 gates). Weights LDS-resident (staged once, 96 KB). gi/pk stay
// L2-warm (never invalidated). Cross-block per step: h (4MB) + partials,
// exchanged ONLY via agent-scope atomic ld/st (device-coherent through L3,
// bypasses non-coherent L2s) -> no threadfence, no cache invalidation.
// Ticket barrier (R7-validated) with explicit vmcnt drain, no fences.
// 256 blocks x 512 thr, 116 KB LDS -> 1 block/CU, all co-resident.

typedef __attribute__((ext_vector_type(8))) _Float16 f16x8;
typedef __attribute__((ext_vector_type(16))) float floatx16;
typedef __attribute__((ext_vector_type(4))) float floatx4;

__device__ unsigned g_bar2 = 0;   // monotonic ticket counter (replay-safe)

__device__ __forceinline__ float sigm_f(float v) { return 1.0f / (1.0f + __expf(-v)); }
__device__ __forceinline__ float tanh_f(float v) { return 2.0f / (1.0f + __expf(-2.0f * v)) - 1.0f; }

__device__ __forceinline__ void async16(void* lds, const void* g) {
    __builtin_amdgcn_global_load_lds(
        (const __attribute__((address_space(1))) void*)g,
        (__attribute__((address_space(3))) void*)lds, 16, 0, 0);
}

__device__ __forceinline__ unsigned long long dev_ld64(const void* p) {
    return __hip_atomic_load((const unsigned long long*)p,
                             __ATOMIC_RELAXED, __HIP_MEMORY_SCOPE_AGENT);
}
__device__ __forceinline__ float dev_ldf(const float* p) {
    return __hip_atomic_load(p, __ATOMIC_RELAXED, __HIP_MEMORY_SCOPE_AGENT);
}
__device__ __forceinline__ void dev_st64(void* p, unsigned long long v) {
    __hip_atomic_store((unsigned long long*)p, v,
                       __ATOMIC_RELAXED, __HIP_MEMORY_SCOPE_AGENT);
}
__device__ __forceinline__ void dev_stf(float* p, float v) {
    __hip_atomic_store(p, v, __ATOMIC_RELAXED, __HIP_MEMORY_SCOPE_AGENT);
}

// Grid barrier for EXACTLY 256 blocks. All cross-block data moves via
// device-scope ops, so NO cache maintenance here: drain stores, ticket, poll.
__device__ __forceinline__ void grid_barrier256() {
    asm volatile("s_waitcnt vmcnt(0)" ::: "memory");  // my stores acked at L3
    __syncthreads();
    if (threadIdx.x == 0) {
        unsigned t = __hip_atomic_fetch_add(&g_bar2, 1u, __ATOMIC_RELAXED,
                                            __HIP_MEMORY_SCOPE_AGENT);
        unsigned target = (t & ~255u) + 256u;
        while (__hip_atomic_load(&g_bar2, __ATOMIC_RELAXED,
                                 __HIP_MEMORY_SCOPE_AGENT) < target)
            __builtin_amdgcn_s_sleep(2);
    }
    __syncthreads();
}

// ---------------- K0: casts + packing + a0 (unchanged, validated) ----------------
__global__ __launch_bounds__(256) void k0_prep(
    const float* __restrict__ z, const float* __restrict__ x,
    const float* __restrict__ x0, const float* __restrict__ W_ia,
    const float* __restrict__ b_ia, const float* __restrict__ W_ih,
    const float* __restrict__ W_hh, const float* __restrict__ W_h0,
    const float* __restrict__ W_out, const float* __restrict__ b_hh,
    _Float16* __restrict__ zx16, _Float16* __restrict__ wcat16,
    _Float16* __restrict__ whh16, float* __restrict__ pk, float* __restrict__ xbuf)
{
    const int ZX = 4096 * 256, WC = 2048 * 256, WH = 1536 * 512, PKN = 512, XB = 4096 * 2;
    const int total = ZX + WC + WH + PKN + XB;
    for (int idx = blockIdx.x * 256 + threadIdx.x; idx < total; idx += gridDim.x * 256) {
        if (idx < ZX) {
            int i = idx >> 8, k = idx & 255;
            float v = (k < 128) ? z[i * 128 + k] : x[i * 128 + (k - 128)];
            zx16[idx] = (_Float16)v;
        } else if (idx < ZX + WC) {
            int j = idx - ZX;
            int n = j >> 8, k = j & 255;
            float v = (n < 512) ? W_h0[n * 256 + k] : W_ih[(n - 512) * 258 + k];
            wcat16[j] = (_Float16)v;
        } else if (idx < ZX + WC + WH) {
            int j = idx - ZX - WC;
            whh16[j] = (_Float16)W_hh[j];
        } else if (idx < ZX + WC + WH + PKN) {
            int jc = idx - ZX - WC - WH;
            float* o = pk + jc * 12;
            o[0] = W_ih[jc * 258 + 256];          o[1] = W_ih[jc * 258 + 257];
            o[2] = W_ih[(512 + jc) * 258 + 256];  o[3] = W_ih[(512 + jc) * 258 + 257];
            o[4] = W_ih[(1024 + jc) * 258 + 256]; o[5] = W_ih[(1024 + jc) * 258 + 257];
            o[6] = b_hh[jc]; o[7] = b_hh[512 + jc]; o[8] = b_hh[1024 + jc];
            o[9] = W_out[jc]; o[10] = W_out[512 + jc]; o[11] = 0.f;
        } else {
            int j = idx - ZX - WC - WH - PKN;
            int i = j >> 1, d = j & 1;
            float s = b_ia[d];
            #pragma unroll
            for (int k2 = 0; k2 < 4; k2++) s += x0[i * 4 + k2] * W_ia[d * 4 + k2];
            xbuf[j] = s;
        }
    }
}

// ---------------- K1: h0 + gi planes (unchanged, validated) ----------------
__global__ __launch_bounds__(256) void k1_precompute(
    const _Float16* __restrict__ zx16, const _Float16* __restrict__ wcat16,
    const float* __restrict__ b_h0, const float* __restrict__ b_ih,
    _Float16* __restrict__ h16a, _Float16* __restrict__ gi16)
{
    __shared__ __align__(16) char smem[24576];
    const uint32_t BOFF = 0, AOFF = 8192;
    int tid = threadIdx.x;
    int w = tid >> 6, lane = tid & 63;
    int half = lane >> 5, l31 = lane & 31;
    int rsub = lane >> 3, csub = lane & 7;
    int Mb = blockIdx.x * 128, Nb = blockIdx.y * 64;

    const _Float16* gsrc[6];
    uint32_t ldso[6];
    #pragma unroll
    for (int j = 0; j < 6; j++) {
        int L = w + 4 * j;
        if (L < 16) {
            int r = L * 8 + rsub;
            gsrc[j] = zx16 + (size_t)(Mb + r) * 256 + ((csub ^ (r & 7)) << 3);
            ldso[j] = AOFF + (uint32_t)L * 1024;
        } else {
            int rb = (L - 16) * 8 + rsub;
            gsrc[j] = wcat16 + (size_t)(Nb + rb) * 256 + ((csub ^ (rb & 7)) << 3);
            ldso[j] = BOFF + (uint32_t)(L - 16) * 1024;
        }
    }

    floatx16 acc0 = {0,0,0,0,0,0,0,0,0,0,0,0,0,0,0,0};
    floatx16 acc1 = {0,0,0,0,0,0,0,0,0,0,0,0,0,0,0,0};

    for (int kc = 0; kc < 4; kc++) {
        #pragma unroll
        for (int j = 0; j < 6; j++) async16(smem + ldso[j], gsrc[j] + kc * 64);
        __syncthreads();
        #pragma unroll
        for (int ks = 0; ks < 4; ks++) {
            int ch = ks * 2 + half;
            int ar = (w << 5) | l31;
            f16x8 a = *(const f16x8*)(smem + AOFF + ((uint32_t)ar << 7) + ((uint32_t)(ch ^ (ar & 7)) << 4));
            uint32_t sw = (uint32_t)(ch ^ (l31 & 7)) << 4;
            f16x8 b0 = *(const f16x8*)(smem + BOFF + ((uint32_t)l31 << 7) + sw);
            f16x8 b1 = *(const f16x8*)(smem + BOFF + ((uint32_t)(32 + l31) << 7) + sw);
            acc0 = __builtin_amdgcn_mfma_f32_32x32x16_f16(a, b0, acc0, 0, 0, 0);
            acc1 = __builtin_amdgcn_mfma_f32_32x32x16_f16(a, b1, acc1, 0, 0, 0);
        }
        __syncthreads();
    }

    #pragma unroll
    for (int nt = 0; nt < 2; nt++) {
        int ncol = Nb + nt * 32 + l31;
        floatx16 acc = nt ? acc1 : acc0;
        #pragma unroll
        for (int reg = 0; reg < 16; reg++) {
            int row = (reg & 3) + 8 * (reg >> 2) + 4 * half;
            size_t i = (size_t)Mb + (w << 5) + row;
            float v = acc[reg];
            if (ncol < 512) {
                h16a[i * 512 + ncol] = (_Float16)(v + b_h0[ncol]);
            } else {
                int c = ncol - 512;
                int g = c >> 9, jc = c & 511;
                gi16[(size_t)g * 2097152 + i * 512 + jc] = (_Float16)(v + b_ih[c]);
            }
        }
    }
}

// ---------------- K2: persistent 12-step GRU, column ownership ----------------
// 256 blocks x 512 thr (8 waves). bx = bid & 15 -> 256 samples; by = bid >> 4
// -> 32 jc cols (x3 gates). LDS: B[96 rows][512 K] fp16 swizzled @0 (96KB),
// hstore[256][32] fp16 @98304 (16KB, this block's h slice, persists across
// steps), xs[256][2] f32 @114688, oac[256][2] f32 @116736. Total 118784.
__global__ __launch_bounds__(512, 1) void k2_roll(
    _Float16* __restrict__ h16a, _Float16* __restrict__ h16b,
    const _Float16* __restrict__ whh16, const _Float16* __restrict__ gi16,
    const float* __restrict__ pk, const float* __restrict__ xbuf,
    float* __restrict__ P0, float* __restrict__ P1,
    float* __restrict__ dout, const float* __restrict__ b_out)
{
    extern __shared__ __align__(16) char smem[];
    const uint32_t BOFF = 0, HST = 98304, XSO = 114688, OAC = 116736;
    const int tid = threadIdx.x;
    const int bid = blockIdx.x;
    const int bx = bid & 15, by = bid >> 4;
    const int M0 = bx * 256, jc0 = by * 32;
    const int wv = tid >> 6, lane = tid & 63;
    const int l15 = lane & 15, q2 = lane >> 4;
    float* xs  = (float*)(smem + XSO);
    float* oacf = (float*)(smem + OAC);

    // ---- one-time: stage B (96 rows x 512 K) into LDS, swizzled ----
    {
        #pragma unroll
        for (int j = 0; j < 12; j++) {
            int r = j * 8 + wv;               // 0..95
            int g = r >> 5, jin = r & 31;
            int n = g * 512 + jc0 + jin;      // global weight row
            int ks_s = lane >> 2, q1 = lane & 3;
            int q = q1 ^ ((r >> 1) & 3);
            const _Float16* src = whh16 + (size_t)n * 512 + ks_s * 32 + q * 8;
            async16(smem + BOFF + (uint32_t)r * 1024, src);
        }
    }
    // ---- one-time: hstore prefill from h0; xs/oac init; pk regs ----
    {
        int row = tid >> 1, ch = (tid & 1) * 16;   // 16 cols per thread
        const unsigned long long* s =
            (const unsigned long long*)(h16a + (size_t)(M0 + row) * 512 + jc0 + ch);
        unsigned long long* dlds =
            (unsigned long long*)(smem + HST + (uint32_t)(row * 32 + ch) * 2);
        dlds[0] = s[0]; dlds[1] = s[1]; dlds[2] = s[2]; dlds[3] = s[3];
        oacf[tid] = 0.f;
    }
    // per-(jt) packed params
    float4 p0v[2], p1v[2], p2v[2]; float wo0[2], wo1[2];
    #pragma unroll
    for (int jt = 0; jt < 2; jt++) {
        int jc = jc0 + jt * 16 + l15;
        const float4* pkp = (const float4*)(pk + (size_t)jc * 12);
        p0v[jt] = pkp[0]; p1v[jt] = pkp[1]; p2v[jt] = pkp[2];
        wo0[jt] = p2v[jt].y; wo1[jt] = p2v[jt].z;
    }
    // A addresses (t-invariant byte offsets into the h buffers)
    size_t aoff0 = ((size_t)(M0 + (wv * 2 + 0) * 16 + l15) * 512) * 2 + (size_t)q2 * 16;
    size_t aoff1 = ((size_t)(M0 + (wv * 2 + 1) * 16 + l15) * 512) * 2 + (size_t)q2 * 16;
    // B read offsets
    uint32_t broff[6];
    #pragma unroll
    for (int g = 0; g < 3; g++)
        #pragma unroll
        for (int jt = 0; jt < 2; jt++) {
            int r = g * 32 + jt * 16 + l15;
            broff[g * 2 + jt] = BOFF + (uint32_t)r * 1024 +
                                ((uint32_t)(q2 ^ ((r >> 1) & 3)) << 4);
        }
    const _Float16* giR = gi16;
    const _Float16* giZ = gi16 + 2097152;
    const _Float16* giN = gi16 + 4194304;
    __syncthreads();   // B staged (vmcnt drained by barrier), hstore/oac ready

    union U { unsigned long long qq[2]; f16x8 v; };

    #pragma unroll 1
    for (int t = 0; t < 12; t++) {
        const _Float16* hcur = (t & 1) ? h16b : h16a;
        _Float16* hnext      = (t & 1) ? h16a : h16b;
        const float* pr      = (t & 1) ? P0 : P1;   // written at t-1
        float* pw            = (t & 1) ? P1 : P0;   // written at t

        // ---- prologue: x_t for 256 samples (+ dout_{t-1}) ----
        {
            int i = tid >> 1, d = tid & 1;
            float v;
            if (t == 0) {
                v = xbuf[(size_t)(M0 + i) * 2 + d];
            } else {
                float s = b_out[d];
                const float* pp = pr + ((size_t)(M0 + i) * 2 + d) * 16;
                #pragma unroll
                for (int k = 0; k < 16; k++) s += dev_ldf(pp + k);
                if (by == 0) dout[((size_t)(M0 + i) * 12 + (t - 1)) * 2 + d] = s;
                v = s;
            }
            xs[tid] = v;
        }
        __syncthreads();

        // ---- GEMM: acc[mt][g][jt] over K=512, A from global (device-scope) ----
        const char* rp0 = (const char*)hcur + aoff0;
        const char* rp1 = (const char*)hcur + aoff1;
        floatx4 acc[2][3][2];
        #pragma unroll
        for (int mt = 0; mt < 2; mt++)
            #pragma unroll
            for (int g = 0; g < 3; g++)
                #pragma unroll
                for (int jt = 0; jt < 2; jt++)
                    acc[mt][g][jt] = (floatx4){0.f, 0.f, 0.f, 0.f};

        U aq[4][2];
        #define ALOAD(S, KS) do { \
            aq[S][0].qq[0] = dev_ld64(rp0 + (KS) * 64); \
            aq[S][0].qq[1] = dev_ld64(rp0 + (KS) * 64 + 8); \
            aq[S][1].qq[0] = dev_ld64(rp1 + (KS) * 64); \
            aq[S][1].qq[1] = dev_ld64(rp1 + (KS) * 64 + 8); \
        } while (0)
        ALOAD(0, 0); ALOAD(1, 1); ALOAD(2, 2);
        #pragma unroll
        for (int ks = 0; ks < 16; ks++) {
            if (ks < 13) { ALOAD((ks + 3) & 3, ks + 3); }
            f16x8 a0 = aq[ks & 3][0].v;
            f16x8 a1 = aq[ks & 3][1].v;
            #pragma unroll
            for (int g = 0; g < 3; g++)
                #pragma unroll
                for (int jt = 0; jt < 2; jt++) {
                    f16x8 b = *(const f16x8*)(smem + broff[g * 2 + jt] + (uint32_t)(ks * 64));
                    acc[0][g][jt] = __builtin_amdgcn_mfma_f32_16x16x32_f16(a0, b, acc[0][g][jt], 0, 0, 0);
                    acc[1][g][jt] = __builtin_amdgcn_mfma_f32_16x16x32_f16(a1, b, acc[1][g][jt], 0, 0, 0);
                }
        }
        #undef ALOAD

        // ---- epilogue: gates, hn -> hstore, out-partials ----
        float po[2][4][2];
        #pragma unroll
        for (int mt = 0; mt < 2; mt++)
            #pragma unroll
            for (int reg = 0; reg < 4; reg++) { po[mt][reg][0] = 0.f; po[mt][reg][1] = 0.f; }

        #pragma unroll
        for (int mt = 0; mt < 2; mt++) {
            #pragma unroll
            for (int jt = 0; jt < 2; jt++) {
                int jc = jc0 + jt * 16 + l15;
                #pragma unroll
                for (int reg = 0; reg < 4; reg++) {
                    int rl = (wv * 2 + mt) * 16 + q2 * 4 + reg;   // local row 0..255
                    size_t ii = (size_t)(M0 + rl);
                    float g0  = (float)giR[ii * 512 + jc];
                    float g1  = (float)giZ[ii * 512 + jc];
                    float g2v = (float)giN[ii * 512 + jc];
                    float x0v = xs[rl * 2], x1v = xs[rl * 2 + 1];
                    _Float16* hp = (_Float16*)(smem + HST + (uint32_t)(rl * 32 + jt * 16 + l15) * 2);
                    float hold = (float)hp[0];
                    float r  = sigm_f(g0 + p0v[jt].x * x0v + p0v[jt].y * x1v + acc[mt][0][jt][reg] + p1v[jt].z);
                    float u  = sigm_f(g1 + p0v[jt].z * x0v + p0v[jt].w * x1v + acc[mt][1][jt][reg] + p1v[jt].w);
                    float nn = tanh_f(g2v + p1v[jt].x * x0v + p1v[jt].y * x1v + r * (acc[mt][2][jt][reg] + p2v[jt].x));
                    float hn = (1.f - u) * nn + u * hold;
                    hp[0] = (_Float16)hn;
                    po[mt][reg][0] += hn * wo0[jt];
                    po[mt][reg][1] += hn * wo1[jt];
                }
            }
        }
        // reduce po over the 16 l15 lanes, accumulate into oac rows
        #pragma unroll
        for (int m = 1; m < 16; m <<= 1)
            #pragma unroll
            for (int mt = 0; mt < 2; mt++)
                #pragma unroll
                for (int reg = 0; reg < 4; reg++) {
                    po[mt][reg][0] += __shfl_xor(po[mt][reg][0], m);
                    po[mt][reg][1] += __shfl_xor(po[mt][reg][1], m);
                }
        if (l15 == 0) {
            #pragma unroll
            for (int mt = 0; mt < 2; mt++)
                #pragma unroll
                for (int reg = 0; reg < 4; reg++) {
                    int rl = (wv * 2 + mt) * 16 + q2 * 4 + reg;
                    atomicAdd(&oacf[rl * 2 + 0], po[mt][reg][0]);
                    atomicAdd(&oacf[rl * 2 + 1], po[mt][reg][1]);
                }
        }
        __syncthreads();   // hstore + oac complete

        // ---- publish h slice (device-scope) + partials; reset oac ----
        {
            int row = tid >> 1, ch = (tid & 1) * 16;
            const unsigned long long* sl =
                (const unsigned long long*)(smem + HST + (uint32_t)(row * 32 + ch) * 2);
            unsigned long long* gd =
                (unsigned long long*)(hnext + (size_t)(M0 + row) * 512 + jc0 + ch);
            dev_st64(gd + 0, sl[0]); dev_st64(gd + 1, sl[1]);
            dev_st64(gd + 2, sl[2]); dev_st64(gd + 3, sl[3]);
            dev_stf(pw + ((size_t)(M0 + row) * 2 + (tid & 1)) * 16 + by, oacf[tid]);
        }
        __syncthreads();
        oacf[tid] = 0.f;
        grid_barrier256();
    }

    // ---- final output out_11 (t=11 wrote P1) ----
    if (by == 0) {
        int i = M0 + (tid >> 1), d = tid & 1;
        float s = b_out[d];
        const float* pp = P1 + ((size_t)i * 2 + d) * 16;
        #pragma unroll
        for (int k = 0; k < 16; k++) s += dev_ldf(pp + k);
        dout[((size_t)i * 12 + 11) * 2 + d] = s;
    }
}

extern "C" void kernel_launch(void* const* d_in, const int* in_sizes, int n_in,
                              void* d_out, int out_size, void* d_ws, size_t ws_size,
                              hipStream_t stream)
{
    const float* z     = (const float*)d_in[0];
    const float* x     = (const float*)d_in[1];
    const float* x0    = (const float*)d_in[2];
    const float* W_ia  = (const float*)d_in[3];
    const float* b_ia  = (const float*)d_in[4];
    const float* W_h0  = (const float*)d_in[5];
    const float* b_h0  = (const float*)d_in[6];
    const float* W_ih  = (const float*)d_in[7];
    const float* b_ih  = (const float*)d_in[8];
    const float* W_hh  = (const float*)d_in[9];
    const float* b_hh  = (const float*)d_in[10];
    const float* W_out = (const float*)d_in[11];
    const float* b_out = (const float*)d_in[12];
    float* dout = (float*)d_out;

    char* ws = (char*)d_ws;
    _Float16* h16a   = (_Float16*)(ws + 0);          // 4 MiB (h0, then ping)
    _Float16* h16b   = (_Float16*)(ws + 4194304);    // 4 MiB (pong)
    _Float16* gi16   = (_Float16*)(ws + 8388608);    // 12 MiB
    _Float16* zx16   = (_Float16*)(ws + 20971520);   // 2 MiB (dead after k1)
    _Float16* wcat16 = (_Float16*)(ws + 23068672);   // 1 MiB (dead after k1)
    _Float16* whh16  = (_Float16*)(ws + 24117248);   // 1.5 MiB
    float*    pk     = (float*)(ws + 25690112);      // 24 KiB
    float*    xbuf   = (float*)(ws + 25714688);      // 32 KiB
    float*    P0     = (float*)(ws + 25747456);      // 512 KiB
    float*    P1     = (float*)(ws + 20971520);      // overlays zx16

    static bool s_attr_done = false;
    if (!s_attr_done) {
        hipFuncSetAttribute((const void*)k2_roll,
                            hipFuncAttributeMaxDynamicSharedMemorySize, 118784);
        s_attr_done = true;
    }

    k0_prep<<<2048, 256, 0, stream>>>(z, x, x0, W_ia, b_ia, W_ih, W_hh, W_h0,
                                      W_out, b_hh, zx16, wcat16, whh16, pk, xbuf);
    k1_precompute<<<dim3(32, 32), 256, 0, stream>>>(zx16, wcat16, b_h0, b_ih, h16a, gi16);
    k2_roll<<<256, 512, 118784, stream>>>(h16a, h16b, whh16, gi16, pk, xbuf,
                                          P0, P1, dout, b_out);
}

// Round 5
// 422.707 us; speedup vs baseline: 1.2541x; 1.2541x over previous
//
#include <hip/hip_runtime.h>
#include <cstdint>
#include <cstddef>

// R10: R9 structure (column-ownership persistent GRU, ticket barrier) with the
// h/partial exchange rebuilt for CACHED consumer loads:
//  - 11 step-indexed h buffers + 12 partial buffers in __device__ static
//    memory (never poisoned by the harness, no address reuse within a launch).
//    Producers write agent-scope (through to L3); consumers use PLAIN vector
//    loads -- safe because kernel-begin invalidates L2 and each address's
//    first cached touch is after its write+barrier.
//  - B-swizzle fixed to slot^(r&15): 64 lanes spread uniformly over all 8
//    16B bank-quads (R9's swizzle left a 16-way conflict, 30.5M cycles).
//  - oacf LDS atomics -> plain stores (rows are wave-exclusive).
// k0/k1 byte-identical to the validated R5 kernels.

typedef __attribute__((ext_vector_type(8))) _Float16 f16x8;
typedef __attribute__((ext_vector_type(16))) float floatx16;
typedef __attribute__((ext_vector_type(4))) float floatx4;

__device__ unsigned g_bar2 = 0;   // monotonic ticket counter (replay-safe)

// Static exchange buffers: outside the workspace, so the harness's buffer
// re-poisoning never touches these addresses.
__device__ __align__(256) _Float16 g_h[11][4096 * 512 + 2048];
__device__ __align__(256) float    g_P[12][4096 * 2 * 16];

__device__ __forceinline__ float sigm_f(float v) { return 1.0f / (1.0f + __expf(-v)); }
__device__ __forceinline__ float tanh_f(float v) { return 2.0f / (1.0f + __expf(-2.0f * v)) - 1.0f; }

__device__ __forceinline__ void async16(void* lds, const void* g) {
    __builtin_amdgcn_global_load_lds(
        (const __attribute__((address_space(1))) void*)g,
        (__attribute__((address_space(3))) void*)lds, 16, 0, 0);
}

__device__ __forceinline__ void dev_st64(void* p, unsigned long long v) {
    __hip_atomic_store((unsigned long long*)p, v,
                       __ATOMIC_RELAXED, __HIP_MEMORY_SCOPE_AGENT);
}
__device__ __forceinline__ void dev_stf(float* p, float v) {
    __hip_atomic_store(p, v, __ATOMIC_RELAXED, __HIP_MEMORY_SCOPE_AGENT);
}

// Grid barrier for EXACTLY 256 blocks (1 block/CU by LDS -> all co-resident).
__device__ __forceinline__ void grid_barrier256() {
    asm volatile("s_waitcnt vmcnt(0)" ::: "memory");  // my stores acked at L3
    __syncthreads();
    if (threadIdx.x == 0) {
        unsigned t = __hip_atomic_fetch_add(&g_bar2, 1u, __ATOMIC_RELAXED,
                                            __HIP_MEMORY_SCOPE_AGENT);
        unsigned target = (t & ~255u) + 256u;
        while (__hip_atomic_load(&g_bar2, __ATOMIC_RELAXED,
                                 __HIP_MEMORY_SCOPE_AGENT) < target)
            __builtin_amdgcn_s_sleep(2);
    }
    __syncthreads();
}

// ---------------- K0: casts + packing + a0 (unchanged, validated) ----------------
__global__ __launch_bounds__(256) void k0_prep(
    const float* __restrict__ z, const float* __restrict__ x,
    const float* __restrict__ x0, const float* __restrict__ W_ia,
    const float* __restrict__ b_ia, const float* __restrict__ W_ih,
    const float* __restrict__ W_hh, const float* __restrict__ W_h0,
    const float* __restrict__ W_out, const float* __restrict__ b_hh,
    _Float16* __restrict__ zx16, _Float16* __restrict__ wcat16,
    _Float16* __restrict__ whh16, float* __restrict__ pk, float* __restrict__ xbuf)
{
    const int ZX = 4096 * 256, WC = 2048 * 256, WH = 1536 * 512, PKN = 512, XB = 4096 * 2;
    const int total = ZX + WC + WH + PKN + XB;
    for (int idx = blockIdx.x * 256 + threadIdx.x; idx < total; idx += gridDim.x * 256) {
        if (idx < ZX) {
            int i = idx >> 8, k = idx & 255;
            float v = (k < 128) ? z[i * 128 + k] : x[i * 128 + (k - 128)];
            zx16[idx] = (_Float16)v;
        } else if (idx < ZX + WC) {
            int j = idx - ZX;
            int n = j >> 8, k = j & 255;
            float v = (n < 512) ? W_h0[n * 256 + k] : W_ih[(n - 512) * 258 + k];
            wcat16[j] = (_Float16)v;
        } else if (idx < ZX + WC + WH) {
            int j = idx - ZX - WC;
            whh16[j] = (_Float16)W_hh[j];
        } else if (idx < ZX + WC + WH + PKN) {
            int jc = idx - ZX - WC - WH;
            float* o = pk + jc * 12;
            o[0] = W_ih[jc * 258 + 256];          o[1] = W_ih[jc * 258 + 257];
            o[2] = W_ih[(512 + jc) * 258 + 256];  o[3] = W_ih[(512 + jc) * 258 + 257];
            o[4] = W_ih[(1024 + jc) * 258 + 256]; o[5] = W_ih[(1024 + jc) * 258 + 257];
            o[6] = b_hh[jc]; o[7] = b_hh[512 + jc]; o[8] = b_hh[1024 + jc];
            o[9] = W_out[jc]; o[10] = W_out[512 + jc]; o[11] = 0.f;
        } else {
            int j = idx - ZX - WC - WH - PKN;
            int i = j >> 1, d = j & 1;
            float s = b_ia[d];
            #pragma unroll
            for (int k2 = 0; k2 < 4; k2++) s += x0[i * 4 + k2] * W_ia[d * 4 + k2];
            xbuf[j] = s;
        }
    }
}

// ---------------- K1: h0 + gi planes (unchanged, validated) ----------------
__global__ __launch_bounds__(256) void k1_precompute(
    const _Float16* __restrict__ zx16, const _Float16* __restrict__ wcat16,
    const float* __restrict__ b_h0, const float* __restrict__ b_ih,
    _Float16* __restrict__ h16a, _Float16* __restrict__ gi16)
{
    __shared__ __align__(16) char smem[24576];
    const uint32_t BOFF = 0, AOFF = 8192;
    int tid = threadIdx.x;
    int w = tid >> 6, lane = tid & 63;
    int half = lane >> 5, l31 = lane & 31;
    int rsub = lane >> 3, csub = lane & 7;
    int Mb = blockIdx.x * 128, Nb = blockIdx.y * 64;

    const _Float16* gsrc[6];
    uint32_t ldso[6];
    #pragma unroll
    for (int j = 0; j < 6; j++) {
        int L = w + 4 * j;
        if (L < 16) {
            int r = L * 8 + rsub;
            gsrc[j] = zx16 + (size_t)(Mb + r) * 256 + ((csub ^ (r & 7)) << 3);
            ldso[j] = AOFF + (uint32_t)L * 1024;
        } else {
            int rb = (L - 16) * 8 + rsub;
            gsrc[j] = wcat16 + (size_t)(Nb + rb) * 256 + ((csub ^ (rb & 7)) << 3);
            ldso[j] = BOFF + (uint32_t)(L - 16) * 1024;
        }
    }

    floatx16 acc0 = {0,0,0,0,0,0,0,0,0,0,0,0,0,0,0,0};
    floatx16 acc1 = {0,0,0,0,0,0,0,0,0,0,0,0,0,0,0,0};

    for (int kc = 0; kc < 4; kc++) {
        #pragma unroll
        for (int j = 0; j < 6; j++) async16(smem + ldso[j], gsrc[j] + kc * 64);
        __syncthreads();
        #pragma unroll
        for (int ks = 0; ks < 4; ks++) {
            int ch = ks * 2 + half;
            int ar = (w << 5) | l31;
            f16x8 a = *(const f16x8*)(smem + AOFF + ((uint32_t)ar << 7) + ((uint32_t)(ch ^ (ar & 7)) << 4));
            uint32_t sw = (uint32_t)(ch ^ (l31 & 7)) << 4;
            f16x8 b0 = *(const f16x8*)(smem + BOFF + ((uint32_t)l31 << 7) + sw);
            f16x8 b1 = *(const f16x8*)(smem + BOFF + ((uint32_t)(32 + l31) << 7) + sw);
            acc0 = __builtin_amdgcn_mfma_f32_32x32x16_f16(a, b0, acc0, 0, 0, 0);
            acc1 = __builtin_amdgcn_mfma_f32_32x32x16_f16(a, b1, acc1, 0, 0, 0);
        }
        __syncthreads();
    }

    #pragma unroll
    for (int nt = 0; nt < 2; nt++) {
        int ncol = Nb + nt * 32 + l31;
        floatx16 acc = nt ? acc1 : acc0;
        #pragma unroll
        for (int reg = 0; reg < 16; reg++) {
            int row = (reg & 3) + 8 * (reg >> 2) + 4 * half;
            size_t i = (size_t)Mb + (w << 5) + row;
            float v = acc[reg];
            if (ncol < 512) {
                h16a[i * 512 + ncol] = (_Float16)(v + b_h0[ncol]);
            } else {
                int c = ncol - 512;
                int g = c >> 9, jc = c & 511;
                gi16[(size_t)g * 2097152 + i * 512 + jc] = (_Float16)(v + b_ih[c]);
            }
        }
    }
}

// ---------------- K2: persistent 12-step GRU, column ownership ----------------
// 256 blocks x 512 thr (8 waves). bx = bid & 15 -> 256 samples; by = bid >> 4
// -> 32 jc cols (x3 gates). LDS: B[96][512]h swizzled @0 (96KB), hstore
// [256][32]h @98304 (16KB), xs[256][2]f @114688, oac[256][2]f @116736.
__global__ __launch_bounds__(512, 1) void k2_seq(
    const _Float16* __restrict__ h16a, const _Float16* __restrict__ whh16,
    const _Float16* __restrict__ gi16, const float* __restrict__ pk,
    const float* __restrict__ xbuf, float* __restrict__ dout,
    const float* __restrict__ b_out)
{
    extern __shared__ __align__(16) char smem[];
    const uint32_t BOFF = 0, HST = 98304, XSO = 114688, OAC = 116736;
    const int tid = threadIdx.x;
    const int bid = blockIdx.x;
    const int bx = bid & 15, by = bid >> 4;
    const int M0 = bx * 256, jc0 = by * 32;
    const int wv = tid >> 6, lane = tid & 63;
    const int l15 = lane & 15, q2 = lane >> 4;
    float* xs  = (float*)(smem + XSO);
    float* oacf = (float*)(smem + OAC);

    // ---- one-time: stage B (96 rows x 512 K) into LDS, full-XOR swizzled ----
    // LDS[r][l16] = W[n][(l16 ^ (r&15)) * 8 ..+8]  (l16 = lane, 16B units)
    {
        #pragma unroll
        for (int j = 0; j < 12; j++) {
            int r = j * 8 + wv;               // 0..95
            int g = r >> 5, jin = r & 31;
            int n = g * 512 + jc0 + jin;      // global weight row
            const _Float16* src = whh16 + (size_t)n * 512 + ((lane ^ (r & 15)) << 3);
            async16(smem + BOFF + (uint32_t)r * 1024, src);
        }
    }
    // ---- one-time: hstore prefill from h0 (plain loads, k1 handoff) ----
    {
        int row = tid >> 1, ch = (tid & 1) * 16;
        const unsigned long long* s =
            (const unsigned long long*)(h16a + (size_t)(M0 + row) * 512 + jc0 + ch);
        unsigned long long* dlds =
            (unsigned long long*)(smem + HST + (uint32_t)(row * 32 + ch) * 2);
        dlds[0] = s[0]; dlds[1] = s[1]; dlds[2] = s[2]; dlds[3] = s[3];
    }
    // per-(jt) packed params
    float4 p0v[2], p1v[2], p2v[2]; float wo0[2], wo1[2];
    #pragma unroll
    for (int jt = 0; jt < 2; jt++) {
        int jc = jc0 + jt * 16 + l15;
        const float4* pkp = (const float4*)(pk + (size_t)jc * 12);
        p0v[jt] = pkp[0]; p1v[jt] = pkp[1]; p2v[jt] = pkp[2];
        wo0[jt] = p2v[jt].y; wo1[jt] = p2v[jt].z;
    }
    // A-fragment byte offsets (t-invariant): row = (wv*2+mt)*16 + l15, k-chunk q2
    size_t aoff0 = ((size_t)(M0 + (wv * 2 + 0) * 16 + l15) * 512) * 2 + (size_t)q2 * 16;
    size_t aoff1 = ((size_t)(M0 + (wv * 2 + 1) * 16 + l15) * 512) * 2 + (size_t)q2 * 16;
    // B read bases: addr(ks) = (base + ((ks>>2)<<8)) ^ ((ks&3)<<6)
    // where base = r*1024 + ((q2 ^ (r&3))<<4) + (((r>>2)&3)<<6)
    uint32_t bbase[6];
    #pragma unroll
    for (int g = 0; g < 3; g++)
        #pragma unroll
        for (int jt = 0; jt < 2; jt++) {
            int r = g * 32 + jt * 16 + l15;
            bbase[g * 2 + jt] = BOFF + (uint32_t)r * 1024 +
                                ((uint32_t)(q2 ^ (r & 3)) << 4) +
                                ((uint32_t)((r >> 2) & 3) << 6);
        }
    const _Float16* giR = gi16;
    const _Float16* giZ = gi16 + 2097152;
    const _Float16* giN = gi16 + 4194304;
    __syncthreads();   // B staged (barrier drains vmcnt), hstore ready

    #pragma unroll 1
    for (int t = 0; t < 12; t++) {
        const _Float16* hcur = (t == 0) ? h16a : &g_h[t - 1][0];

        // ---- prologue: x_t for 256 samples (+ dout_{t-1}); plain loads ----
        {
            int i = tid >> 1, d = tid & 1;
            float v;
            if (t == 0) {
                v = xbuf[(size_t)(M0 + i) * 2 + d];
            } else {
                const float4* p = (const float4*)(&g_P[t - 1][0] + ((size_t)(M0 + i) * 2 + d) * 16);
                float4 a = p[0], b = p[1], c = p[2], e = p[3];
                v = b_out[d] + a.x + a.y + a.z + a.w + b.x + b.y + b.z + b.w
                             + c.x + c.y + c.z + c.w + e.x + e.y + e.z + e.w;
                if (by == 0) dout[((size_t)(M0 + i) * 12 + (t - 1)) * 2 + d] = v;
            }
            xs[tid] = v;
        }
        __syncthreads();

        // ---- GEMM: K=512, A from global (plain cached loads, depth-3 queue) ----
        const char* rp0 = (const char*)hcur + aoff0;
        const char* rp1 = (const char*)hcur + aoff1;
        floatx4 acc[2][3][2];
        #pragma unroll
        for (int mt = 0; mt < 2; mt++)
            #pragma unroll
            for (int g = 0; g < 3; g++)
                #pragma unroll
                for (int jt = 0; jt < 2; jt++)
                    acc[mt][g][jt] = (floatx4){0.f, 0.f, 0.f, 0.f};

        f16x8 aq[4][2];
        #define ALOAD(S, KS) do { \
            aq[S][0] = *(const f16x8*)(rp0 + (KS) * 64); \
            aq[S][1] = *(const f16x8*)(rp1 + (KS) * 64); \
        } while (0)
        ALOAD(0, 0); ALOAD(1, 1); ALOAD(2, 2);
        #pragma unroll
        for (int ks = 0; ks < 16; ks++) {
            if (ks < 13) { ALOAD((ks + 3) & 3, ks + 3); }
            f16x8 a0 = aq[ks & 3][0];
            f16x8 a1 = aq[ks & 3][1];
            const uint32_t kadd = (uint32_t)((ks >> 2) << 8);
            const uint32_t kxor = (uint32_t)((ks & 3) << 6);
            #pragma unroll
            for (int g = 0; g < 3; g++)
                #pragma unroll
                for (int jt = 0; jt < 2; jt++) {
                    f16x8 b = *(const f16x8*)(smem + ((bbase[g * 2 + jt] + kadd) ^ kxor));
                    acc[0][g][jt] = __builtin_amdgcn_mfma_f32_16x16x32_f16(a0, b, acc[0][g][jt], 0, 0, 0);
                    acc[1][g][jt] = __builtin_amdgcn_mfma_f32_16x16x32_f16(a1, b, acc[1][g][jt], 0, 0, 0);
                }
        }
        #undef ALOAD

        // ---- epilogue: gates, hn -> hstore, out-partials (wave-exclusive rows) ----
        float po[2][4][2];
        #pragma unroll
        for (int mt = 0; mt < 2; mt++)
            #pragma unroll
            for (int reg = 0; reg < 4; reg++) { po[mt][reg][0] = 0.f; po[mt][reg][1] = 0.f; }

        #pragma unroll
        for (int mt = 0; mt < 2; mt++) {
            #pragma unroll
            for (int jt = 0; jt < 2; jt++) {
                int jc = jc0 + jt * 16 + l15;
                #pragma unroll
                for (int reg = 0; reg < 4; reg++) {
                    int rl = (wv * 2 + mt) * 16 + q2 * 4 + reg;   // local row 0..255
                    size_t ii = (size_t)(M0 + rl);
                    float g0  = (float)giR[ii * 512 + jc];
                    float g1  = (float)giZ[ii * 512 + jc];
                    float g2v = (float)giN[ii * 512 + jc];
                    float x0v = xs[rl * 2], x1v = xs[rl * 2 + 1];
                    _Float16* hp = (_Float16*)(smem + HST + (uint32_t)(rl * 32 + jt * 16 + l15) * 2);
                    float hold = (float)hp[0];
                    float r  = sigm_f(g0 + p0v[jt].x * x0v + p0v[jt].y * x1v + acc[mt][0][jt][reg] + p1v[jt].z);
                    float u  = sigm_f(g1 + p0v[jt].z * x0v + p0v[jt].w * x1v + acc[mt][1][jt][reg] + p1v[jt].w);
                    float nn = tanh_f(g2v + p1v[jt].x * x0v + p1v[jt].y * x1v + r * (acc[mt][2][jt][reg] + p2v[jt].x));
                    float hn = (1.f - u) * nn + u * hold;
                    hp[0] = (_Float16)hn;
                    po[mt][reg][0] += hn * wo0[jt];
                    po[mt][reg][1] += hn * wo1[jt];
                }
            }
        }
        // reduce po over the 16 l15 lanes; rows are wave-exclusive -> plain store
        #pragma unroll
        for (int m = 1; m < 16; m <<= 1)
            #pragma unroll
            for (int mt = 0; mt < 2; mt++)
                #pragma unroll
                for (int reg = 0; reg < 4; reg++) {
                    po[mt][reg][0] += __shfl_xor(po[mt][reg][0], m);
                    po[mt][reg][1] += __shfl_xor(po[mt][reg][1], m);
                }
        if (l15 == 0) {
            #pragma unroll
            for (int mt = 0; mt < 2; mt++)
                #pragma unroll
                for (int reg = 0; reg < 4; reg++) {
                    int rl = (wv * 2 + mt) * 16 + q2 * 4 + reg;
                    ((float2*)oacf)[rl] = make_float2(po[mt][reg][0], po[mt][reg][1]);
                }
        }
        __syncthreads();   // hstore + oacf complete across waves

        // ---- publish h slice (t<11) + partials (agent-scope, through to L3) ----
        if (t < 11) {
            int row = tid >> 1, ch = (tid & 1) * 16;
            const unsigned long long* sl =
                (const unsigned long long*)(smem + HST + (uint32_t)(row * 32 + ch) * 2);
            unsigned long long* gd =
                (unsigned long long*)(&g_h[t][0] + (size_t)(M0 + row) * 512 + jc0 + ch);
            dev_st64(gd + 0, sl[0]); dev_st64(gd + 1, sl[1]);
            dev_st64(gd + 2, sl[2]); dev_st64(gd + 3, sl[3]);
        }
        dev_stf(&g_P[t][0] + ((size_t)(M0 + (tid >> 1)) * 2 + (tid & 1)) * 16 + by,
                oacf[tid]);
        grid_barrier256();
    }

    // ---- final output out_11 (t=11 wrote g_P[11]) ----
    if (by == 0) {
        int i = M0 + (tid >> 1), d = tid & 1;
        const float4* p = (const float4*)(&g_P[11][0] + ((size_t)i * 2 + d) * 16);
        float4 a = p[0], b = p[1], c = p[2], e = p[3];
        float v = b_out[d] + a.x + a.y + a.z + a.w + b.x + b.y + b.z + b.w
                           + c.x + c.y + c.z + c.w + e.x + e.y + e.z + e.w;
        dout[((size_t)i * 12 + 11) * 2 + d] = v;
    }
}

extern "C" void kernel_launch(void* const* d_in, const int* in_sizes, int n_in,
                              void* d_out, int out_size, void* d_ws, size_t ws_size,
                              hipStream_t stream)
{
    const float* z     = (const float*)d_in[0];
    const float* x     = (const float*)d_in[1];
    const float* x0    = (const float*)d_in[2];
    const float* W_ia  = (const float*)d_in[3];
    const float* b_ia  = (const float*)d_in[4];
    const float* W_h0  = (const float*)d_in[5];
    const float* b_h0  = (const float*)d_in[6];
    const float* W_ih  = (const float*)d_in[7];
    const float* b_ih  = (const float*)d_in[8];
    const float* W_hh  = (const float*)d_in[9];
    const float* b_hh  = (const float*)d_in[10];
    const float* W_out = (const float*)d_in[11];
    const float* b_out = (const float*)d_in[12];
    float* dout = (float*)d_out;

    char* ws = (char*)d_ws;
    _Float16* h16a   = (_Float16*)(ws + 0);          // 4 MiB (h0 from k1)
    _Float16* gi16   = (_Float16*)(ws + 8388608);    // 12 MiB
    _Float16* zx16   = (_Float16*)(ws + 20971520);   // 2 MiB (dead after k1)
    _Float16* wcat16 = (_Float16*)(ws + 23068672);   // 1 MiB (dead after k1)
    _Float16* whh16  = (_Float16*)(ws + 24117248);   // 1.5 MiB
    float*    pk     = (float*)(ws + 25690112);      // 24 KiB
    float*    xbuf   = (float*)(ws + 25714688);      // 32 KiB

    static bool s_attr_done = false;
    if (!s_attr_done) {
        hipFuncSetAttribute((const void*)k2_seq,
                            hipFuncAttributeMaxDynamicSharedMemorySize, 118784);
        s_attr_done = true;
    }

    k0_prep<<<2048, 256, 0, stream>>>(z, x, x0, W_ia, b_ia, W_ih, W_hh, W_h0,
                                      W_out, b_hh, zx16, wcat16, whh16, pk, xbuf);
    k1_precompute<<<dim3(32, 32), 256, 0, stream>>>(zx16, wcat16, b_h0, b_ih, h16a, gi16);
    k2_seq<<<256, 512, 118784, stream>>>(h16a, whh16, gi16, pk, xbuf, dout, b_out);
}

// Round 6
// 287.489 us; speedup vs baseline: 1.8440x; 1.4703x over previous
//
#include <hip/hip_runtime.h>
#include <cstdint>
#include <cstddef>

// R11: XCD-local persistent GRU. 256 blocks x 512 thr, 1 block/CU (forced by
// 116 KB LDS) => exactly 32 blocks per XCD. Blocks discover their physical
// XCD via s_getreg(HW_REG_XCC_ID) and self-register into slots; each XCD
// hosts 2 independent groups of 16 blocks; a group owns 256 samples, a block
// owns 32 h-cols x 3 gates. All per-step exchange (h, partials) is PLAIN
// stores/loads within one coherent L2 -- no write-through, no L3 latency.
// Barrier is a 16-block per-group ticket. GEMM/epilogue/swizzles byte-level
// identical to the validated R10 kernel. k0/k1 unchanged (validated).

typedef __attribute__((ext_vector_type(8))) _Float16 f16x8;
typedef __attribute__((ext_vector_type(16))) float floatx16;
typedef __attribute__((ext_vector_type(4))) float floatx4;

__device__ unsigned g_cnt[8 * 64];     // per-XCD registration tickets (padded)
__device__ unsigned g_gbar[16 * 64];   // per-group barrier counters (padded)

// Static exchange buffers (outside workspace; step-indexed => first-touch-per-
// launch addresses, validated R10). g_h: 11 x 4MB, g_P: 12 x 512KB.
__device__ __align__(256) _Float16 g_h[11][4096 * 512 + 2048];
__device__ __align__(256) float    g_P[12][4096 * 2 * 16];

__device__ __forceinline__ float sigm_f(float v) { return 1.0f / (1.0f + __expf(-v)); }
__device__ __forceinline__ float tanh_f(float v) { return 2.0f / (1.0f + __expf(-2.0f * v)) - 1.0f; }

__device__ __forceinline__ void async16(void* lds, const void* g) {
    __builtin_amdgcn_global_load_lds(
        (const __attribute__((address_space(1))) void*)g,
        (__attribute__((address_space(3))) void*)lds, 16, 0, 0);
}

// Per-group barrier: EXACTLY 16 co-resident blocks (same XCD). Data moves via
// the shared L2; the flag via L3 atomics. vmcnt(0) first => data at L2 before
// the flag is raised; peer sees flag then hits L2. Monotonic => replay-safe.
__device__ __forceinline__ void group_barrier16(unsigned gidx) {
    asm volatile("s_waitcnt vmcnt(0)" ::: "memory");
    __syncthreads();
    if (threadIdx.x == 0) {
        unsigned* ctr = &g_gbar[gidx * 64];
        unsigned t = __hip_atomic_fetch_add(ctr, 1u, __ATOMIC_RELAXED,
                                            __HIP_MEMORY_SCOPE_AGENT);
        unsigned target = (t & ~15u) + 16u;
        while (__hip_atomic_load(ctr, __ATOMIC_RELAXED,
                                 __HIP_MEMORY_SCOPE_AGENT) < target)
            __builtin_amdgcn_s_sleep(1);
    }
    __syncthreads();
}

// ---------------- K0: casts + packing + a0 (unchanged, validated) ----------------
__global__ __launch_bounds__(256) void k0_prep(
    const float* __restrict__ z, const float* __restrict__ x,
    const float* __restrict__ x0, const float* __restrict__ W_ia,
    const float* __restrict__ b_ia, const float* __restrict__ W_ih,
    const float* __restrict__ W_hh, const float* __restrict__ W_h0,
    const float* __restrict__ W_out, const float* __restrict__ b_hh,
    _Float16* __restrict__ zx16, _Float16* __restrict__ wcat16,
    _Float16* __restrict__ whh16, float* __restrict__ pk, float* __restrict__ xbuf)
{
    const int ZX = 4096 * 256, WC = 2048 * 256, WH = 1536 * 512, PKN = 512, XB = 4096 * 2;
    const int total = ZX + WC + WH + PKN + XB;
    for (int idx = blockIdx.x * 256 + threadIdx.x; idx < total; idx += gridDim.x * 256) {
        if (idx < ZX) {
            int i = idx >> 8, k = idx & 255;
            float v = (k < 128) ? z[i * 128 + k] : x[i * 128 + (k - 128)];
            zx16[idx] = (_Float16)v;
        } else if (idx < ZX + WC) {
            int j = idx - ZX;
            int n = j >> 8, k = j & 255;
            float v = (n < 512) ? W_h0[n * 256 + k] : W_ih[(n - 512) * 258 + k];
            wcat16[j] = (_Float16)v;
        } else if (idx < ZX + WC + WH) {
            int j = idx - ZX - WC;
            whh16[j] = (_Float16)W_hh[j];
        } else if (idx < ZX + WC + WH + PKN) {
            int jc = idx - ZX - WC - WH;
            float* o = pk + jc * 12;
            o[0] = W_ih[jc * 258 + 256];          o[1] = W_ih[jc * 258 + 257];
            o[2] = W_ih[(512 + jc) * 258 + 256];  o[3] = W_ih[(512 + jc) * 258 + 257];
            o[4] = W_ih[(1024 + jc) * 258 + 256]; o[5] = W_ih[(1024 + jc) * 258 + 257];
            o[6] = b_hh[jc]; o[7] = b_hh[512 + jc]; o[8] = b_hh[1024 + jc];
            o[9] = W_out[jc]; o[10] = W_out[512 + jc]; o[11] = 0.f;
        } else {
            int j = idx - ZX - WC - WH - PKN;
            int i = j >> 1, d = j & 1;
            float s = b_ia[d];
            #pragma unroll
            for (int k2 = 0; k2 < 4; k2++) s += x0[i * 4 + k2] * W_ia[d * 4 + k2];
            xbuf[j] = s;
        }
    }
}

// ---------------- K1: h0 + gi planes (unchanged, validated) ----------------
__global__ __launch_bounds__(256) void k1_precompute(
    const _Float16* __restrict__ zx16, const _Float16* __restrict__ wcat16,
    const float* __restrict__ b_h0, const float* __restrict__ b_ih,
    _Float16* __restrict__ h16a, _Float16* __restrict__ gi16)
{
    __shared__ __align__(16) char smem[24576];
    const uint32_t BOFF = 0, AOFF = 8192;
    int tid = threadIdx.x;
    int w = tid >> 6, lane = tid & 63;
    int half = lane >> 5, l31 = lane & 31;
    int rsub = lane >> 3, csub = lane & 7;
    int Mb = blockIdx.x * 128, Nb = blockIdx.y * 64;

    const _Float16* gsrc[6];
    uint32_t ldso[6];
    #pragma unroll
    for (int j = 0; j < 6; j++) {
        int L = w + 4 * j;
        if (L < 16) {
            int r = L * 8 + rsub;
            gsrc[j] = zx16 + (size_t)(Mb + r) * 256 + ((csub ^ (r & 7)) << 3);
            ldso[j] = AOFF + (uint32_t)L * 1024;
        } else {
            int rb = (L - 16) * 8 + rsub;
            gsrc[j] = wcat16 + (size_t)(Nb + rb) * 256 + ((csub ^ (rb & 7)) << 3);
            ldso[j] = BOFF + (uint32_t)(L - 16) * 1024;
        }
    }

    floatx16 acc0 = {0,0,0,0,0,0,0,0,0,0,0,0,0,0,0,0};
    floatx16 acc1 = {0,0,0,0,0,0,0,0,0,0,0,0,0,0,0,0};

    for (int kc = 0; kc < 4; kc++) {
        #pragma unroll
        for (int j = 0; j < 6; j++) async16(smem + ldso[j], gsrc[j] + kc * 64);
        __syncthreads();
        #pragma unroll
        for (int ks = 0; ks < 4; ks++) {
            int ch = ks * 2 + half;
            int ar = (w << 5) | l31;
            f16x8 a = *(const f16x8*)(smem + AOFF + ((uint32_t)ar << 7) + ((uint32_t)(ch ^ (ar & 7)) << 4));
            uint32_t sw = (uint32_t)(ch ^ (l31 & 7)) << 4;
            f16x8 b0 = *(const f16x8*)(smem + BOFF + ((uint32_t)l31 << 7) + sw);
            f16x8 b1 = *(const f16x8*)(smem + BOFF + ((uint32_t)(32 + l31) << 7) + sw);
            acc0 = __builtin_amdgcn_mfma_f32_32x32x16_f16(a, b0, acc0, 0, 0, 0);
            acc1 = __builtin_amdgcn_mfma_f32_32x32x16_f16(a, b1, acc1, 0, 0, 0);
        }
        __syncthreads();
    }

    #pragma unroll
    for (int nt = 0; nt < 2; nt++) {
        int ncol = Nb + nt * 32 + l31;
        floatx16 acc = nt ? acc1 : acc0;
        #pragma unroll
        for (int reg = 0; reg < 16; reg++) {
            int row = (reg & 3) + 8 * (reg >> 2) + 4 * half;
            size_t i = (size_t)Mb + (w << 5) + row;
            float v = acc[reg];
            if (ncol < 512) {
                h16a[i * 512 + ncol] = (_Float16)(v + b_h0[ncol]);
            } else {
                int c = ncol - 512;
                int g = c >> 9, jc = c & 511;
                gi16[(size_t)g * 2097152 + i * 512 + jc] = (_Float16)(v + b_ih[c]);
            }
        }
    }
}

// ---------------- K2: XCD-local persistent 12-step GRU ----------------
// LDS: B[96][512]h swizzled @0 (96KB), hstore[256][32]h @98304 (16KB),
// xs[256][2]f @114688, oac[256][2]f @116736, slot bcast @118784.
__global__ __launch_bounds__(512, 1) void k2_xcd(
    const _Float16* __restrict__ h16a, const _Float16* __restrict__ whh16,
    const _Float16* __restrict__ gi16, const float* __restrict__ pk,
    const float* __restrict__ xbuf, float* __restrict__ dout,
    const float* __restrict__ b_out)
{
    extern __shared__ __align__(16) char smem[];
    const uint32_t BOFF = 0, HST = 98304, XSO = 114688, OAC = 116736, SLO = 118784;
    const int tid = threadIdx.x;
    float* xs  = (float*)(smem + XSO);
    float* oacf = (float*)(smem + OAC);

    // ---- XCD discovery + registration (1 blk/CU => exactly 32 blks/XCD) ----
    unsigned xcc;
    asm volatile("s_getreg_b32 %0, hwreg(HW_REG_XCC_ID)" : "=s"(xcc));
    xcc &= 7u;
    if (tid == 0) {
        unsigned s = __hip_atomic_fetch_add(&g_cnt[xcc * 64], 1u, __ATOMIC_RELAXED,
                                            __HIP_MEMORY_SCOPE_AGENT) & 31u;
        *(unsigned*)(smem + SLO) = s;
    }
    __syncthreads();
    const unsigned slot = *(volatile unsigned*)(smem + SLO);
    const int shalf = slot >> 4, cgrp = slot & 15;
    const unsigned gidx = xcc * 2 + shalf;      // 0..15, 16 blocks each
    const int M0 = (int)gidx * 256;             // group's 256 samples
    const int jc0 = cgrp * 32;                  // block's 32 h-cols (x3 gates)

    const int wv = tid >> 6, lane = tid & 63;
    const int l15 = lane & 15, q2 = lane >> 4;

    // ---- one-time: stage B (96 rows x 512 K) into LDS, full-XOR swizzled ----
    {
        #pragma unroll
        for (int j = 0; j < 12; j++) {
            int r = j * 8 + wv;               // 0..95
            int g = r >> 5, jin = r & 31;
            int n = g * 512 + jc0 + jin;      // global weight row
            const _Float16* src = whh16 + (size_t)n * 512 + ((lane ^ (r & 15)) << 3);
            async16(smem + BOFF + (uint32_t)r * 1024, src);
        }
    }
    // ---- one-time: hstore prefill from h0 (plain loads, k1 handoff) ----
    {
        int row = tid >> 1, ch = (tid & 1) * 16;
        const unsigned long long* s =
            (const unsigned long long*)(h16a + (size_t)(M0 + row) * 512 + jc0 + ch);
        unsigned long long* dlds =
            (unsigned long long*)(smem + HST + (uint32_t)(row * 32 + ch) * 2);
        dlds[0] = s[0]; dlds[1] = s[1]; dlds[2] = s[2]; dlds[3] = s[3];
    }
    // per-(jt) packed params
    float4 p0v[2], p1v[2], p2v[2]; float wo0[2], wo1[2];
    #pragma unroll
    for (int jt = 0; jt < 2; jt++) {
        int jc = jc0 + jt * 16 + l15;
        const float4* pkp = (const float4*)(pk + (size_t)jc * 12);
        p0v[jt] = pkp[0]; p1v[jt] = pkp[1]; p2v[jt] = pkp[2];
        wo0[jt] = p2v[jt].y; wo1[jt] = p2v[jt].z;
    }
    // A-fragment byte offsets (t-invariant): row = (wv*2+mt)*16 + l15, chunk q2
    size_t aoff0 = ((size_t)(M0 + (wv * 2 + 0) * 16 + l15) * 512) * 2 + (size_t)q2 * 16;
    size_t aoff1 = ((size_t)(M0 + (wv * 2 + 1) * 16 + l15) * 512) * 2 + (size_t)q2 * 16;
    // B read bases (validated R10 swizzle)
    uint32_t bbase[6];
    #pragma unroll
    for (int g = 0; g < 3; g++)
        #pragma unroll
        for (int jt = 0; jt < 2; jt++) {
            int r = g * 32 + jt * 16 + l15;
            bbase[g * 2 + jt] = BOFF + (uint32_t)r * 1024 +
                                ((uint32_t)(q2 ^ (r & 3)) << 4) +
                                ((uint32_t)((r >> 2) & 3) << 6);
        }
    const _Float16* giR = gi16;
    const _Float16* giZ = gi16 + 2097152;
    const _Float16* giN = gi16 + 4194304;
    __syncthreads();   // B staged (compiler drains vmcnt before barrier)

    #pragma unroll 1
    for (int t = 0; t < 12; t++) {
        const _Float16* hcur = (t == 0) ? h16a : &g_h[t - 1][0];

        // ---- prologue: x_t for the group's 256 samples (+ dout_{t-1}) ----
        {
            int i = tid >> 1, d = tid & 1;
            float v;
            if (t == 0) {
                v = xbuf[(size_t)(M0 + i) * 2 + d];
            } else {
                const float4* p = (const float4*)(&g_P[t - 1][0] + ((size_t)(M0 + i) * 2 + d) * 16);
                float4 a = p[0], b = p[1], c = p[2], e = p[3];
                v = b_out[d] + a.x + a.y + a.z + a.w + b.x + b.y + b.z + b.w
                             + c.x + c.y + c.z + c.w + e.x + e.y + e.z + e.w;
                if (cgrp == 0) dout[((size_t)(M0 + i) * 12 + (t - 1)) * 2 + d] = v;
            }
            xs[tid] = v;
        }
        __syncthreads();

        // ---- GEMM: K=512, A from L2-local global (depth-3 queue) ----
        const char* rp0 = (const char*)hcur + aoff0;
        const char* rp1 = (const char*)hcur + aoff1;
        floatx4 acc[2][3][2];
        #pragma unroll
        for (int mt = 0; mt < 2; mt++)
            #pragma unroll
            for (int g = 0; g < 3; g++)
                #pragma unroll
                for (int jt = 0; jt < 2; jt++)
                    acc[mt][g][jt] = (floatx4){0.f, 0.f, 0.f, 0.f};

        f16x8 aq[4][2];
        #define ALOAD(S, KS) do { \
            aq[S][0] = *(const f16x8*)(rp0 + (KS) * 64); \
            aq[S][1] = *(const f16x8*)(rp1 + (KS) * 64); \
        } while (0)
        ALOAD(0, 0); ALOAD(1, 1); ALOAD(2, 2);
        #pragma unroll
        for (int ks = 0; ks < 16; ks++) {
            if (ks < 13) { ALOAD((ks + 3) & 3, ks + 3); }
            f16x8 a0 = aq[ks & 3][0];
            f16x8 a1 = aq[ks & 3][1];
            const uint32_t kadd = (uint32_t)((ks >> 2) << 8);
            const uint32_t kxor = (uint32_t)((ks & 3) << 6);
            #pragma unroll
            for (int g = 0; g < 3; g++)
                #pragma unroll
                for (int jt = 0; jt < 2; jt++) {
                    f16x8 b = *(const f16x8*)(smem + ((bbase[g * 2 + jt] + kadd) ^ kxor));
                    acc[0][g][jt] = __builtin_amdgcn_mfma_f32_16x16x32_f16(a0, b, acc[0][g][jt], 0, 0, 0);
                    acc[1][g][jt] = __builtin_amdgcn_mfma_f32_16x16x32_f16(a1, b, acc[1][g][jt], 0, 0, 0);
                }
        }
        #undef ALOAD

        // ---- epilogue: gates, hn -> hstore, out-partials ----
        float po[2][4][2];
        #pragma unroll
        for (int mt = 0; mt < 2; mt++)
            #pragma unroll
            for (int reg = 0; reg < 4; reg++) { po[mt][reg][0] = 0.f; po[mt][reg][1] = 0.f; }

        #pragma unroll
        for (int mt = 0; mt < 2; mt++) {
            #pragma unroll
            for (int jt = 0; jt < 2; jt++) {
                int jc = jc0 + jt * 16 + l15;
                #pragma unroll
                for (int reg = 0; reg < 4; reg++) {
                    int rl = (wv * 2 + mt) * 16 + q2 * 4 + reg;   // local row 0..255
                    size_t ii = (size_t)(M0 + rl);
                    float g0  = (float)giR[ii * 512 + jc];
                    float g1  = (float)giZ[ii * 512 + jc];
                    float g2v = (float)giN[ii * 512 + jc];
                    float x0v = xs[rl * 2], x1v = xs[rl * 2 + 1];
                    _Float16* hp = (_Float16*)(smem + HST + (uint32_t)(rl * 32 + jt * 16 + l15) * 2);
                    float hold = (float)hp[0];
                    float r  = sigm_f(g0 + p0v[jt].x * x0v + p0v[jt].y * x1v + acc[mt][0][jt][reg] + p1v[jt].z);
                    float u  = sigm_f(g1 + p0v[jt].z * x0v + p0v[jt].w * x1v + acc[mt][1][jt][reg] + p1v[jt].w);
                    float nn = tanh_f(g2v + p1v[jt].x * x0v + p1v[jt].y * x1v + r * (acc[mt][2][jt][reg] + p2v[jt].x));
                    float hn = (1.f - u) * nn + u * hold;
                    hp[0] = (_Float16)hn;
                    po[mt][reg][0] += hn * wo0[jt];
                    po[mt][reg][1] += hn * wo1[jt];
                }
            }
        }
        #pragma unroll
        for (int m = 1; m < 16; m <<= 1)
            #pragma unroll
            for (int mt = 0; mt < 2; mt++)
                #pragma unroll
                for (int reg = 0; reg < 4; reg++) {
                    po[mt][reg][0] += __shfl_xor(po[mt][reg][0], m);
                    po[mt][reg][1] += __shfl_xor(po[mt][reg][1], m);
                }
        if (l15 == 0) {
            #pragma unroll
            for (int mt = 0; mt < 2; mt++)
                #pragma unroll
                for (int reg = 0; reg < 4; reg++) {
                    int rl = (wv * 2 + mt) * 16 + q2 * 4 + reg;
                    ((float2*)oacf)[rl] = make_float2(po[mt][reg][0], po[mt][reg][1]);
                }
        }
        __syncthreads();   // hstore + oacf complete across waves

        // ---- publish h slice (t<11) + partials: PLAIN stores -> local L2 ----
        if (t < 11) {
            int row = tid >> 1, ch = (tid & 1) * 16;
            const unsigned long long* sl =
                (const unsigned long long*)(smem + HST + (uint32_t)(row * 32 + ch) * 2);
            unsigned long long* gd =
                (unsigned long long*)(&g_h[t][0] + (size_t)(M0 + row) * 512 + jc0 + ch);
            gd[0] = sl[0]; gd[1] = sl[1]; gd[2] = sl[2]; gd[3] = sl[3];
        }
        g_P[t][((size_t)(M0 + (tid >> 1)) * 2 + (tid & 1)) * 16 + cgrp] = oacf[tid];
        group_barrier16(gidx);
    }

    // ---- final output out_11 (t=11 wrote g_P[11]; barrier passed) ----
    if (cgrp == 0) {
        int i = M0 + (tid >> 1), d = tid & 1;
        const float4* p = (const float4*)(&g_P[11][0] + ((size_t)i * 2 + d) * 16);
        float4 a = p[0], b = p[1], c = p[2], e = p[3];
        float v = b_out[d] + a.x + a.y + a.z + a.w + b.x + b.y + b.z + b.w
                           + c.x + c.y + c.z + c.w + e.x + e.y + e.z + e.w;
        dout[((size_t)i * 12 + 11) * 2 + d] = v;
    }
}

extern "C" void kernel_launch(void* const* d_in, const int* in_sizes, int n_in,
                              void* d_out, int out_size, void* d_ws, size_t ws_size,
                              hipStream_t stream)
{
    const float* z     = (const float*)d_in[0];
    const float* x     = (const float*)d_in[1];
    const float* x0    = (const float*)d_in[2];
    const float* W_ia  = (const float*)d_in[3];
    const float* b_ia  = (const float*)d_in[4];
    const float* W_h0  = (const float*)d_in[5];
    const float* b_h0  = (const float*)d_in[6];
    const float* W_ih  = (const float*)d_in[7];
    const float* b_ih  = (const float*)d_in[8];
    const float* W_hh  = (const float*)d_in[9];
    const float* b_hh  = (const float*)d_in[10];
    const float* W_out = (const float*)d_in[11];
    const float* b_out = (const float*)d_in[12];
    float* dout = (float*)d_out;

    char* ws = (char*)d_ws;
    _Float16* h16a   = (_Float16*)(ws + 0);          // 4 MiB (h0 from k1)
    _Float16* gi16   = (_Float16*)(ws + 8388608);    // 12 MiB
    _Float16* zx16   = (_Float16*)(ws + 20971520);   // 2 MiB (dead after k1)
    _Float16* wcat16 = (_Float16*)(ws + 23068672);   // 1 MiB (dead after k1)
    _Float16* whh16  = (_Float16*)(ws + 24117248);   // 1.5 MiB
    float*    pk     = (float*)(ws + 25690112);      // 24 KiB
    float*    xbuf   = (float*)(ws + 25714688);      // 32 KiB

    static bool s_attr_done = false;
    if (!s_attr_done) {
        hipFuncSetAttribute((const void*)k2_xcd,
                            hipFuncAttributeMaxDynamicSharedMemorySize, 118848);
        s_attr_done = true;
    }

    k0_prep<<<2048, 256, 0, stream>>>(z, x, x0, W_ia, b_ia, W_ih, W_hh, W_h0,
                                      W_out, b_hh, zx16, wcat16, whh16, pk, xbuf);
    k1_precompute<<<dim3(32, 32), 256, 0, stream>>>(zx16, wcat16, b_h0, b_ih, h16a, gi16);
    k2_xcd<<<256, 512, 118848, stream>>>(h16a, whh16, gi16, pk, xbuf, dout, b_out);
}